// Round 14
// baseline (124.011 us; speedup 1.0000x reference)
//
#include <hip/hip_runtime.h>

#define B_DIM 512
#define F_DIM 128
#define L_DIM 1024
#define K_CLS 8
#define EPS 1e-5f
#define NROWS (B_DIM * F_DIM)     // 65536
#define GRID  2048
#define CHUNK 32                  // rows per block (contiguous, same b)

typedef float vf4 __attribute__((ext_vector_type(4)));

// ws layout: stats table 2048 floats (8 KiB), then sync counter+flag (2 uints)
#define ST_SQ (K_CLS * F_DIM)

__device__ __forceinline__ uint bf16r(float f) {            // RNE bf16 bits
    uint u = __float_as_uint(f);
    return (u + 0x7FFFu + ((u >> 16) & 1u)) >> 16;
}
__device__ __forceinline__ uint pk(float a, float b) {      // pack 2 bf16
    return bf16r(a) | (bf16r(b) << 16);
}
__device__ __forceinline__ float unlo(uint u) { return __uint_as_float(u << 16); }
__device__ __forceinline__ float unhi(uint u) { return __uint_as_float(u & 0xFFFF0000u); }

// Each wave owns 8 rows. Retention across the (hand-rolled, fully inlined)
// grid sync: rows 0,1 -> VGPR bf16 (16 explicit scalars); rows 2,3 -> LDS bf16;
// rows 4..7 -> re-read from global (MALL-served). Rows 0..3 NT-loaded so they
// don't occupy MALL; rows 4..7 loaded normally so they do.
__global__ __launch_bounds__(256, 8) void cbn_fused(const float* __restrict__ x,
                                                    const int* __restrict__ labels,
                                                    const float* __restrict__ weight,
                                                    const float* __restrict__ bias,
                                                    float* __restrict__ stats,
                                                    uint* __restrict__ gsync,
                                                    float* __restrict__ y) {
    const int tid  = threadIdx.x;
    const int wave = tid >> 6;
    const int lane = tid & 63;
    const int r0   = blockIdx.x * CHUNK;      // 32 contiguous rows, same b
    const int b0   = r0 >> 7;
    const int f0   = r0 & (F_DIM - 1);
    const int k    = labels[b0];              // block-uniform

    __shared__ uint2 ldsb[8][256];            // 16 KiB: 2 bf16 rows per wave
    __shared__ float s_sc[CHUNK], s_sh[CHUNK];
    __shared__ int   s_cnt;

    uint pA0, pA1, pA2, pA3, pA4, pA5, pA6, pA7;   // row 0 bf16
    uint pB0, pB1, pB2, pB3, pB4, pB5, pB6, pB7;   // row 1 bf16

    const vf4* xw = reinterpret_cast<const vf4*>(x) + (size_t)(r0 + wave * 8) * (L_DIM / 4);

    // ---- Phase 1: row sums for own 8 rows -> atomicAdd into [k][f] table ----
#pragma unroll
    for (int i = 0; i < 8; ++i) {
        vf4 v0, v1, v2, v3;
        if (i < 4) {   // retained rows: NT load (won't be re-read from memory)
            v0 = __builtin_nontemporal_load(&xw[i * 256 + 0 * 64 + lane]);
            v1 = __builtin_nontemporal_load(&xw[i * 256 + 1 * 64 + lane]);
            v2 = __builtin_nontemporal_load(&xw[i * 256 + 2 * 64 + lane]);
            v3 = __builtin_nontemporal_load(&xw[i * 256 + 3 * 64 + lane]);
        } else {       // re-read rows: normal load -> allocate in MALL
            v0 = xw[i * 256 + 0 * 64 + lane];
            v1 = xw[i * 256 + 1 * 64 + lane];
            v2 = xw[i * 256 + 2 * 64 + lane];
            v3 = xw[i * 256 + 3 * 64 + lane];
        }

        if (i == 0) {
            pA0 = pk(v0.x, v0.y); pA1 = pk(v0.z, v0.w);
            pA2 = pk(v1.x, v1.y); pA3 = pk(v1.z, v1.w);
            pA4 = pk(v2.x, v2.y); pA5 = pk(v2.z, v2.w);
            pA6 = pk(v3.x, v3.y); pA7 = pk(v3.z, v3.w);
        }
        if (i == 1) {
            pB0 = pk(v0.x, v0.y); pB1 = pk(v0.z, v0.w);
            pB2 = pk(v1.x, v1.y); pB3 = pk(v1.z, v1.w);
            pB4 = pk(v2.x, v2.y); pB5 = pk(v2.z, v2.w);
            pB6 = pk(v3.x, v3.y); pB7 = pk(v3.z, v3.w);
        }
        if (i == 2 || i == 3) {
            const int slot = wave * 2 + (i - 2);
            ldsb[slot][0 * 64 + lane] = make_uint2(pk(v0.x, v0.y), pk(v0.z, v0.w));
            ldsb[slot][1 * 64 + lane] = make_uint2(pk(v1.x, v1.y), pk(v1.z, v1.w));
            ldsb[slot][2 * 64 + lane] = make_uint2(pk(v2.x, v2.y), pk(v2.z, v2.w));
            ldsb[slot][3 * 64 + lane] = make_uint2(pk(v3.x, v3.y), pk(v3.z, v3.w));
        }

        float s  = (v0.x + v0.y + v0.z + v0.w) + (v1.x + v1.y + v1.z + v1.w)
                 + (v2.x + v2.y + v2.z + v2.w) + (v3.x + v3.y + v3.z + v3.w);
        float s2 = (v0.x*v0.x + v0.y*v0.y + v0.z*v0.z + v0.w*v0.w)
                 + (v1.x*v1.x + v1.y*v1.y + v1.z*v1.z + v1.w*v1.w)
                 + (v2.x*v2.x + v2.y*v2.y + v2.z*v2.z + v2.w*v2.w)
                 + (v3.x*v3.x + v3.y*v3.y + v3.z*v3.z + v3.w*v3.w);
#pragma unroll
        for (int m = 32; m >= 1; m >>= 1) {
            s  += __shfl_xor(s, m);
            s2 += __shfl_xor(s2, m);
        }
        if (lane == 0) {
            const int f = f0 + wave * 8 + i;
            atomicAdd(&stats[k * F_DIM + f], s);
            atomicAdd(&stats[ST_SQ + k * F_DIM + f], s2);
        }
    }

    // ---- Hand-rolled inlined grid barrier (no function call -> no ABI spill) ----
    __syncthreads();
    if (tid == 0) {
        __threadfence();                                   // release
        const uint old = atomicAdd(&gsync[0], 1u);
        if (old == (uint)GRID - 1u) {
            __hip_atomic_store(&gsync[1], 1u, __ATOMIC_RELEASE, __HIP_MEMORY_SCOPE_AGENT);
        } else {
            while (__hip_atomic_load(&gsync[1], __ATOMIC_RELAXED, __HIP_MEMORY_SCOPE_AGENT) == 0u) {
                __builtin_amdgcn_s_sleep(16);
            }
        }
        __threadfence();                                   // acquire
    }
    __syncthreads();

    // ---- Phase 2: per-block finalize (own k, own 32 f's) ----
    if (tid == 0) s_cnt = 0;
    __syncthreads();
    {
        int c = (labels[tid] == k) + (labels[tid + 256] == k);
#pragma unroll
        for (int m = 32; m >= 1; m >>= 1) c += __shfl_xor(c, m);
        if (lane == 0) atomicAdd(&s_cnt, c);
    }
    __syncthreads();
    if (tid < CHUNK) {
        const int f = f0 + tid;
        const float cnt  = fmaxf((float)s_cnt * (float)L_DIM, 1.0f);
        const float sum  = __hip_atomic_load(&stats[k * F_DIM + f], __ATOMIC_RELAXED, __HIP_MEMORY_SCOPE_AGENT);
        const float sq   = __hip_atomic_load(&stats[ST_SQ + k * F_DIM + f], __ATOMIC_RELAXED, __HIP_MEMORY_SCOPE_AGENT);
        const float mean = sum / cnt;
        const float var  = sq / cnt - mean * mean;
        const float inv  = rsqrtf(var + EPS);
        const float sc   = inv * weight[k * F_DIM + f];
        s_sc[tid] = sc;
        s_sh[tid] = bias[k * F_DIM + f] - mean * sc;
    }
    __syncthreads();

    // ---- Phase 3: apply own 8 rows ----
    vf4* yw = reinterpret_cast<vf4*>(y) + (size_t)(r0 + wave * 8) * (L_DIM / 4);

    {   // row 0 from pA*
        const float sc = s_sc[wave * 8 + 0];
        const float sh = s_sh[wave * 8 + 0];
        vf4 o;
        o.x = unlo(pA0)*sc+sh; o.y = unhi(pA0)*sc+sh; o.z = unlo(pA1)*sc+sh; o.w = unhi(pA1)*sc+sh;
        __builtin_nontemporal_store(o, &yw[0 * 256 + 0 * 64 + lane]);
        o.x = unlo(pA2)*sc+sh; o.y = unhi(pA2)*sc+sh; o.z = unlo(pA3)*sc+sh; o.w = unhi(pA3)*sc+sh;
        __builtin_nontemporal_store(o, &yw[0 * 256 + 1 * 64 + lane]);
        o.x = unlo(pA4)*sc+sh; o.y = unhi(pA4)*sc+sh; o.z = unlo(pA5)*sc+sh; o.w = unhi(pA5)*sc+sh;
        __builtin_nontemporal_store(o, &yw[0 * 256 + 2 * 64 + lane]);
        o.x = unlo(pA6)*sc+sh; o.y = unhi(pA6)*sc+sh; o.z = unlo(pA7)*sc+sh; o.w = unhi(pA7)*sc+sh;
        __builtin_nontemporal_store(o, &yw[0 * 256 + 3 * 64 + lane]);
    }
    {   // row 1 from pB*
        const float sc = s_sc[wave * 8 + 1];
        const float sh = s_sh[wave * 8 + 1];
        vf4 o;
        o.x = unlo(pB0)*sc+sh; o.y = unhi(pB0)*sc+sh; o.z = unlo(pB1)*sc+sh; o.w = unhi(pB1)*sc+sh;
        __builtin_nontemporal_store(o, &yw[1 * 256 + 0 * 64 + lane]);
        o.x = unlo(pB2)*sc+sh; o.y = unhi(pB2)*sc+sh; o.z = unlo(pB3)*sc+sh; o.w = unhi(pB3)*sc+sh;
        __builtin_nontemporal_store(o, &yw[1 * 256 + 1 * 64 + lane]);
        o.x = unlo(pB4)*sc+sh; o.y = unhi(pB4)*sc+sh; o.z = unlo(pB5)*sc+sh; o.w = unhi(pB5)*sc+sh;
        __builtin_nontemporal_store(o, &yw[1 * 256 + 2 * 64 + lane]);
        o.x = unlo(pB6)*sc+sh; o.y = unhi(pB6)*sc+sh; o.z = unlo(pB7)*sc+sh; o.w = unhi(pB7)*sc+sh;
        __builtin_nontemporal_store(o, &yw[1 * 256 + 3 * 64 + lane]);
    }
#pragma unroll
    for (int i = 2; i < 4; ++i) {     // rows 2,3 from LDS bf16
        const int slot = wave * 2 + (i - 2);
        const float sc = s_sc[wave * 8 + i];
        const float sh = s_sh[wave * 8 + i];
#pragma unroll
        for (int j = 0; j < 4; ++j) {
            uint2 u = ldsb[slot][j * 64 + lane];
            vf4 o;
            o.x = unlo(u.x) * sc + sh;
            o.y = unhi(u.x) * sc + sh;
            o.z = unlo(u.y) * sc + sh;
            o.w = unhi(u.y) * sc + sh;
            __builtin_nontemporal_store(o, &yw[i * 256 + j * 64 + lane]);
        }
    }
#pragma unroll
    for (int i = 4; i < 8; ++i) {     // rows 4..7 re-read (MALL-served)
        const float sc = s_sc[wave * 8 + i];
        const float sh = s_sh[wave * 8 + i];
#pragma unroll
        for (int j = 0; j < 4; ++j) {
            vf4 v = xw[i * 256 + j * 64 + lane];
            vf4 o;
            o.x = v.x * sc + sh;
            o.y = v.y * sc + sh;
            o.z = v.z * sc + sh;
            o.w = v.w * sc + sh;
            __builtin_nontemporal_store(o, &yw[i * 256 + j * 64 + lane]);
        }
    }
}

// ================= Fallback path (R6 structure, proven ~127 µs) =================
#define ST_SQ_FB    NROWS
#define ST_SCALE_FB (2 * NROWS)
#define ST_SHIFT_FB (2 * NROWS + K_CLS * F_DIM)

__global__ __launch_bounds__(256) void cbn_stats_fb(const float* __restrict__ x,
                                                    float* __restrict__ st) {
    const int wave = threadIdx.x >> 6;
    const int lane = threadIdx.x & 63;
    const int row  = blockIdx.x * 4 + wave;
    const int b = row >> 7;
    const int f = row & (F_DIM - 1);
    const vf4* x4 = reinterpret_cast<const vf4*>(x) + (size_t)row * (L_DIM / 4);
    float s = 0.f, s2 = 0.f;
#pragma unroll
    for (int i = 0; i < 4; ++i) {
        vf4 v = x4[i * 64 + lane];
        s  += v.x + v.y + v.z + v.w;
        s2 += v.x * v.x + v.y * v.y + v.z * v.z + v.w * v.w;
    }
#pragma unroll
    for (int m = 32; m >= 1; m >>= 1) {
        s  += __shfl_xor(s, m);
        s2 += __shfl_xor(s2, m);
    }
    if (lane == 0) {
        st[f * B_DIM + b]            = s;
        st[ST_SQ_FB + f * B_DIM + b] = s2;
    }
}

__global__ __launch_bounds__(512) void cbn_finalize_fb(const int* __restrict__ labels,
                                                       const float* __restrict__ weight,
                                                       const float* __restrict__ bias,
                                                       float* __restrict__ st) {
    __shared__ float ssum[K_CLS], ssq[K_CLS];
    __shared__ int   cnt[K_CLS];
    const int f = blockIdx.x;
    const int b = threadIdx.x;
    if (b < K_CLS) { ssum[b] = 0.f; ssq[b] = 0.f; cnt[b] = 0; }
    __syncthreads();
    const int k = labels[b];
    atomicAdd(&ssum[k], st[f * B_DIM + b]);
    atomicAdd(&ssq[k],  st[ST_SQ_FB + f * B_DIM + b]);
    atomicAdd(&cnt[k], 1);
    __syncthreads();
    if (b < K_CLS) {
        const float c = fmaxf((float)cnt[b] * (float)L_DIM, 1.0f);
        const float mean = ssum[b] / c;
        const float var  = ssq[b] / c - mean * mean;
        const float inv  = rsqrtf(var + EPS);
        const float sc   = inv * weight[b * F_DIM + f];
        st[ST_SCALE_FB + b * F_DIM + f] = sc;
        st[ST_SHIFT_FB + b * F_DIM + f] = bias[b * F_DIM + f] - mean * sc;
    }
}

#define APPLY_ROWS 4
__global__ __launch_bounds__(256) void cbn_apply_fb(const float* __restrict__ x,
                                                    const int* __restrict__ labels,
                                                    const float* __restrict__ st,
                                                    float* __restrict__ y) {
    const int nBlocks = NROWS / APPLY_ROWS;
    const int blk = nBlocks - 1 - blockIdx.x;
    const int row0 = blk * APPLY_ROWS;
#pragma unroll
    for (int it = 0; it < APPLY_ROWS; ++it) {
        const int row = row0 + it;
        const int b = row >> 7;
        const int f = row & (F_DIM - 1);
        const int k = labels[b];
        const float sc = st[ST_SCALE_FB + k * F_DIM + f];
        const float sh = st[ST_SHIFT_FB + k * F_DIM + f];
        const size_t i4 = (size_t)row * (L_DIM / 4) + threadIdx.x;
        vf4 v = reinterpret_cast<const vf4*>(x)[i4];
        vf4 o;
        o.x = v.x * sc + sh;
        o.y = v.y * sc + sh;
        o.z = v.z * sc + sh;
        o.w = v.w * sc + sh;
        __builtin_nontemporal_store(o, &reinterpret_cast<vf4*>(y)[i4]);
    }
}

extern "C" void kernel_launch(void* const* d_in, const int* in_sizes, int n_in,
                              void* d_out, int out_size, void* d_ws, size_t ws_size,
                              hipStream_t stream) {
    const float* x      = (const float*)d_in[0];
    const int*   labels = (const int*)d_in[1];
    const float* weight = (const float*)d_in[2];
    const float* bias   = (const float*)d_in[3];
    float* y  = (float*)d_out;
    float* ws = (float*)d_ws;
    uint*  gs = (uint*)((char*)d_ws + 2 * K_CLS * F_DIM * sizeof(float));

    int blocksPerCU = 0;
    hipError_t qerr = hipOccupancyMaxActiveBlocksPerMultiprocessor(
        &blocksPerCU, (const void*)cbn_fused, 256, 0);
    const bool coop_ok = (qerr == hipSuccess) && (blocksPerCU * 256 >= GRID);

    if (coop_ok) {
        // zero stats table + sync counter/flag
        hipMemsetAsync(ws, 0, 2 * K_CLS * F_DIM * sizeof(float) + 2 * sizeof(uint), stream);
        void* args[] = { (void*)&x, (void*)&labels, (void*)&weight, (void*)&bias,
                         (void*)&ws, (void*)&gs, (void*)&y };
        hipLaunchCooperativeKernel((const void*)cbn_fused, dim3(GRID), dim3(256),
                                   args, 0, stream);
    } else {
        cbn_stats_fb<<<NROWS / 4, 256, 0, stream>>>(x, ws);
        cbn_finalize_fb<<<F_DIM, 512, 0, stream>>>(labels, weight, bias, ws);
        cbn_apply_fb<<<NROWS / APPLY_ROWS, 256, 0, stream>>>(x, labels, ws, y);
    }
}

// Round 15
// 123.848 us; speedup vs baseline: 1.0013x; 1.0013x over previous
//
#include <hip/hip_runtime.h>

#define B_DIM 512
#define F_DIM 128
#define L_DIM 1024
#define K_CLS 8
#define EPS 1e-5f
#define NROWS (B_DIM * F_DIM)     // 65536
#define GRID  2048
#define CHUNK 32                  // rows per block (contiguous, same b)

typedef float vf4 __attribute__((ext_vector_type(4)));

#define ST_SQ (K_CLS * F_DIM)

__device__ __forceinline__ uint bf16r(float f) {
    uint u = __float_as_uint(f);
    return (u + 0x7FFFu + ((u >> 16) & 1u)) >> 16;
}
__device__ __forceinline__ uint pk(float a, float b) {
    return bf16r(a) | (bf16r(b) << 16);
}
__device__ __forceinline__ float unlo(uint u) { return __uint_as_float(u << 16); }
__device__ __forceinline__ float unhi(uint u) { return __uint_as_float(u & 0xFFFF0000u); }

__device__ __forceinline__ void rowstat(vf4 v0, vf4 v1, vf4 v2, vf4 v3,
                                        int lane, int f, int k,
                                        float* __restrict__ stats) {
    float s  = (v0.x + v0.y + v0.z + v0.w) + (v1.x + v1.y + v1.z + v1.w)
             + (v2.x + v2.y + v2.z + v2.w) + (v3.x + v3.y + v3.z + v3.w);
    float s2 = (v0.x*v0.x + v0.y*v0.y + v0.z*v0.z + v0.w*v0.w)
             + (v1.x*v1.x + v1.y*v1.y + v1.z*v1.z + v1.w*v1.w)
             + (v2.x*v2.x + v2.y*v2.y + v2.z*v2.z + v2.w*v2.w)
             + (v3.x*v3.x + v3.y*v3.y + v3.z*v3.z + v3.w*v3.w);
#pragma unroll
    for (int m = 32; m >= 1; m >>= 1) {
        s  += __shfl_xor(s, m);
        s2 += __shfl_xor(s2, m);
    }
    if (lane == 0) {
        atomicAdd(&stats[k * F_DIM + f], s);
        atomicAdd(&stats[ST_SQ + k * F_DIM + f], s2);
    }
}

// Each wave owns 8 rows. rows 4..7: re-read via MALL (normal loads, unroll 1).
// rows 2,3: LDS bf16. rows 1,0: VGPR bf16, loaded LAST (short live range).
__global__ __launch_bounds__(256, 8) void cbn_fused(const float* __restrict__ x,
                                                    const int* __restrict__ labels,
                                                    const float* __restrict__ weight,
                                                    const float* __restrict__ bias,
                                                    float* __restrict__ stats,
                                                    uint* __restrict__ gsync,
                                                    float* __restrict__ y) {
    const int tid  = threadIdx.x;
    const int wave = tid >> 6;
    const int lane = tid & 63;
    const int r0   = blockIdx.x * CHUNK;
    const int b0   = r0 >> 7;
    const int f0   = r0 & (F_DIM - 1);
    const int k    = labels[b0];

    __shared__ uint2 ldsb[8][256];            // 16 KiB
    __shared__ float s_sc[CHUNK], s_sh[CHUNK];
    __shared__ int   s_cnt;

    const vf4* xw = reinterpret_cast<const vf4*>(x) + (size_t)(r0 + wave * 8) * (L_DIM / 4);

    // ---- Phase 1a: rows 4..7 (re-read later from MALL), bounded pressure ----
#pragma unroll 1
    for (int i = 4; i < 8; ++i) {
        vf4 v0 = xw[i * 256 + 0 * 64 + lane];
        vf4 v1 = xw[i * 256 + 1 * 64 + lane];
        vf4 v2 = xw[i * 256 + 2 * 64 + lane];
        vf4 v3 = xw[i * 256 + 3 * 64 + lane];
        rowstat(v0, v1, v2, v3, lane, f0 + wave * 8 + i, k, stats);
    }
    // ---- Phase 1b: rows 2,3 -> LDS bf16 (NT loads: won't be re-read) ----
#pragma unroll 1
    for (int i = 2; i < 4; ++i) {
        vf4 v0 = __builtin_nontemporal_load(&xw[i * 256 + 0 * 64 + lane]);
        vf4 v1 = __builtin_nontemporal_load(&xw[i * 256 + 1 * 64 + lane]);
        vf4 v2 = __builtin_nontemporal_load(&xw[i * 256 + 2 * 64 + lane]);
        vf4 v3 = __builtin_nontemporal_load(&xw[i * 256 + 3 * 64 + lane]);
        const int slot = wave * 2 + (i - 2);
        ldsb[slot][0 * 64 + lane] = make_uint2(pk(v0.x, v0.y), pk(v0.z, v0.w));
        ldsb[slot][1 * 64 + lane] = make_uint2(pk(v1.x, v1.y), pk(v1.z, v1.w));
        ldsb[slot][2 * 64 + lane] = make_uint2(pk(v2.x, v2.y), pk(v2.z, v2.w));
        ldsb[slot][3 * 64 + lane] = make_uint2(pk(v3.x, v3.y), pk(v3.z, v3.w));
        rowstat(v0, v1, v2, v3, lane, f0 + wave * 8 + i, k, stats);
    }
    // ---- Phase 1c: row 1 then row 0 -> VGPR bf16, loaded last ----
    uint pB0, pB1, pB2, pB3, pB4, pB5, pB6, pB7;
    {
        vf4 v0 = __builtin_nontemporal_load(&xw[1 * 256 + 0 * 64 + lane]);
        vf4 v1 = __builtin_nontemporal_load(&xw[1 * 256 + 1 * 64 + lane]);
        vf4 v2 = __builtin_nontemporal_load(&xw[1 * 256 + 2 * 64 + lane]);
        vf4 v3 = __builtin_nontemporal_load(&xw[1 * 256 + 3 * 64 + lane]);
        pB0 = pk(v0.x, v0.y); pB1 = pk(v0.z, v0.w);
        pB2 = pk(v1.x, v1.y); pB3 = pk(v1.z, v1.w);
        pB4 = pk(v2.x, v2.y); pB5 = pk(v2.z, v2.w);
        pB6 = pk(v3.x, v3.y); pB7 = pk(v3.z, v3.w);
        rowstat(v0, v1, v2, v3, lane, f0 + wave * 8 + 1, k, stats);
    }
    uint pA0, pA1, pA2, pA3, pA4, pA5, pA6, pA7;
    {
        vf4 v0 = __builtin_nontemporal_load(&xw[0 * 256 + 0 * 64 + lane]);
        vf4 v1 = __builtin_nontemporal_load(&xw[0 * 256 + 1 * 64 + lane]);
        vf4 v2 = __builtin_nontemporal_load(&xw[0 * 256 + 2 * 64 + lane]);
        vf4 v3 = __builtin_nontemporal_load(&xw[0 * 256 + 3 * 64 + lane]);
        pA0 = pk(v0.x, v0.y); pA1 = pk(v0.z, v0.w);
        pA2 = pk(v1.x, v1.y); pA3 = pk(v1.z, v1.w);
        pA4 = pk(v2.x, v2.y); pA5 = pk(v2.z, v2.w);
        pA6 = pk(v3.x, v3.y); pA7 = pk(v3.z, v3.w);
        rowstat(v0, v1, v2, v3, lane, f0 + wave * 8 + 0, k, stats);
    }

    // ---- Inlined grid barrier (no call) ----
    __syncthreads();
    if (tid == 0) {
        __threadfence();
        const uint old = atomicAdd(&gsync[0], 1u);
        if (old == (uint)GRID - 1u) {
            __hip_atomic_store(&gsync[1], 1u, __ATOMIC_RELEASE, __HIP_MEMORY_SCOPE_AGENT);
        } else {
            while (__hip_atomic_load(&gsync[1], __ATOMIC_RELAXED, __HIP_MEMORY_SCOPE_AGENT) == 0u) {
                __builtin_amdgcn_s_sleep(16);
            }
        }
        __threadfence();
    }
    __syncthreads();

    // ---- Phase 2: per-block finalize ----
    if (tid == 0) s_cnt = 0;
    __syncthreads();
    {
        int c = (labels[tid] == k) + (labels[tid + 256] == k);
#pragma unroll
        for (int m = 32; m >= 1; m >>= 1) c += __shfl_xor(c, m);
        if (lane == 0) atomicAdd(&s_cnt, c);
    }
    __syncthreads();
    if (tid < CHUNK) {
        const int f = f0 + tid;
        const float cnt  = fmaxf((float)s_cnt * (float)L_DIM, 1.0f);
        const float sum  = __hip_atomic_load(&stats[k * F_DIM + f], __ATOMIC_RELAXED, __HIP_MEMORY_SCOPE_AGENT);
        const float sq   = __hip_atomic_load(&stats[ST_SQ + k * F_DIM + f], __ATOMIC_RELAXED, __HIP_MEMORY_SCOPE_AGENT);
        const float mean = sum / cnt;
        const float var  = sq / cnt - mean * mean;
        const float inv  = rsqrtf(var + EPS);
        const float sc   = inv * weight[k * F_DIM + f];
        s_sc[tid] = sc;
        s_sh[tid] = bias[k * F_DIM + f] - mean * sc;
    }
    __syncthreads();

    // ---- Phase 3: VGPR rows first (kill retention regs), then LDS, then MALL ----
    vf4* yw = reinterpret_cast<vf4*>(y) + (size_t)(r0 + wave * 8) * (L_DIM / 4);
    {
        const float sc = s_sc[wave * 8 + 0];
        const float sh = s_sh[wave * 8 + 0];
        vf4 o;
        o.x = unlo(pA0)*sc+sh; o.y = unhi(pA0)*sc+sh; o.z = unlo(pA1)*sc+sh; o.w = unhi(pA1)*sc+sh;
        __builtin_nontemporal_store(o, &yw[0 * 256 + 0 * 64 + lane]);
        o.x = unlo(pA2)*sc+sh; o.y = unhi(pA2)*sc+sh; o.z = unlo(pA3)*sc+sh; o.w = unhi(pA3)*sc+sh;
        __builtin_nontemporal_store(o, &yw[0 * 256 + 1 * 64 + lane]);
        o.x = unlo(pA4)*sc+sh; o.y = unhi(pA4)*sc+sh; o.z = unlo(pA5)*sc+sh; o.w = unhi(pA5)*sc+sh;
        __builtin_nontemporal_store(o, &yw[0 * 256 + 2 * 64 + lane]);
        o.x = unlo(pA6)*sc+sh; o.y = unhi(pA6)*sc+sh; o.z = unlo(pA7)*sc+sh; o.w = unhi(pA7)*sc+sh;
        __builtin_nontemporal_store(o, &yw[0 * 256 + 3 * 64 + lane]);
    }
    {
        const float sc = s_sc[wave * 8 + 1];
        const float sh = s_sh[wave * 8 + 1];
        vf4 o;
        o.x = unlo(pB0)*sc+sh; o.y = unhi(pB0)*sc+sh; o.z = unlo(pB1)*sc+sh; o.w = unhi(pB1)*sc+sh;
        __builtin_nontemporal_store(o, &yw[1 * 256 + 0 * 64 + lane]);
        o.x = unlo(pB2)*sc+sh; o.y = unhi(pB2)*sc+sh; o.z = unlo(pB3)*sc+sh; o.w = unhi(pB3)*sc+sh;
        __builtin_nontemporal_store(o, &yw[1 * 256 + 1 * 64 + lane]);
        o.x = unlo(pB4)*sc+sh; o.y = unhi(pB4)*sc+sh; o.z = unlo(pB5)*sc+sh; o.w = unhi(pB5)*sc+sh;
        __builtin_nontemporal_store(o, &yw[1 * 256 + 2 * 64 + lane]);
        o.x = unlo(pB6)*sc+sh; o.y = unhi(pB6)*sc+sh; o.z = unlo(pB7)*sc+sh; o.w = unhi(pB7)*sc+sh;
        __builtin_nontemporal_store(o, &yw[1 * 256 + 3 * 64 + lane]);
    }
#pragma unroll 1
    for (int i = 2; i < 4; ++i) {
        const int slot = wave * 2 + (i - 2);
        const float sc = s_sc[wave * 8 + i];
        const float sh = s_sh[wave * 8 + i];
#pragma unroll
        for (int j = 0; j < 4; ++j) {
            uint2 u = ldsb[slot][j * 64 + lane];
            vf4 o;
            o.x = unlo(u.x) * sc + sh;
            o.y = unhi(u.x) * sc + sh;
            o.z = unlo(u.y) * sc + sh;
            o.w = unhi(u.y) * sc + sh;
            __builtin_nontemporal_store(o, &yw[i * 256 + j * 64 + lane]);
        }
    }
#pragma unroll 1
    for (int i = 4; i < 8; ++i) {
        const float sc = s_sc[wave * 8 + i];
        const float sh = s_sh[wave * 8 + i];
        vf4 v0 = xw[i * 256 + 0 * 64 + lane];
        vf4 v1 = xw[i * 256 + 1 * 64 + lane];
        vf4 v2 = xw[i * 256 + 2 * 64 + lane];
        vf4 v3 = xw[i * 256 + 3 * 64 + lane];
        vf4 o;
        o.x = v0.x*sc+sh; o.y = v0.y*sc+sh; o.z = v0.z*sc+sh; o.w = v0.w*sc+sh;
        __builtin_nontemporal_store(o, &yw[i * 256 + 0 * 64 + lane]);
        o.x = v1.x*sc+sh; o.y = v1.y*sc+sh; o.z = v1.z*sc+sh; o.w = v1.w*sc+sh;
        __builtin_nontemporal_store(o, &yw[i * 256 + 1 * 64 + lane]);
        o.x = v2.x*sc+sh; o.y = v2.y*sc+sh; o.z = v2.z*sc+sh; o.w = v2.w*sc+sh;
        __builtin_nontemporal_store(o, &yw[i * 256 + 2 * 64 + lane]);
        o.x = v3.x*sc+sh; o.y = v3.y*sc+sh; o.z = v3.z*sc+sh; o.w = v3.w*sc+sh;
        __builtin_nontemporal_store(o, &yw[i * 256 + 3 * 64 + lane]);
    }
}

// ================= Fallback path (R6 structure, proven ~127 µs) =================
#define ST_SQ_FB    NROWS
#define ST_SCALE_FB (2 * NROWS)
#define ST_SHIFT_FB (2 * NROWS + K_CLS * F_DIM)

__global__ __launch_bounds__(256) void cbn_stats_fb(const float* __restrict__ x,
                                                    float* __restrict__ st) {
    const int wave = threadIdx.x >> 6;
    const int lane = threadIdx.x & 63;
    const int row  = blockIdx.x * 4 + wave;
    const int b = row >> 7;
    const int f = row & (F_DIM - 1);
    const vf4* x4 = reinterpret_cast<const vf4*>(x) + (size_t)row * (L_DIM / 4);
    float s = 0.f, s2 = 0.f;
#pragma unroll
    for (int i = 0; i < 4; ++i) {
        vf4 v = x4[i * 64 + lane];
        s  += v.x + v.y + v.z + v.w;
        s2 += v.x * v.x + v.y * v.y + v.z * v.z + v.w * v.w;
    }
#pragma unroll
    for (int m = 32; m >= 1; m >>= 1) {
        s  += __shfl_xor(s, m);
        s2 += __shfl_xor(s2, m);
    }
    if (lane == 0) {
        st[f * B_DIM + b]            = s;
        st[ST_SQ_FB + f * B_DIM + b] = s2;
    }
}

__global__ __launch_bounds__(512) void cbn_finalize_fb(const int* __restrict__ labels,
                                                       const float* __restrict__ weight,
                                                       const float* __restrict__ bias,
                                                       float* __restrict__ st) {
    __shared__ float ssum[K_CLS], ssq[K_CLS];
    __shared__ int   cnt[K_CLS];
    const int f = blockIdx.x;
    const int b = threadIdx.x;
    if (b < K_CLS) { ssum[b] = 0.f; ssq[b] = 0.f; cnt[b] = 0; }
    __syncthreads();
    const int k = labels[b];
    atomicAdd(&ssum[k], st[f * B_DIM + b]);
    atomicAdd(&ssq[k],  st[ST_SQ_FB + f * B_DIM + b]);
    atomicAdd(&cnt[k], 1);
    __syncthreads();
    if (b < K_CLS) {
        const float c = fmaxf((float)cnt[b] * (float)L_DIM, 1.0f);
        const float mean = ssum[b] / c;
        const float var  = ssq[b] / c - mean * mean;
        const float inv  = rsqrtf(var + EPS);
        const float sc   = inv * weight[b * F_DIM + f];
        st[ST_SCALE_FB + b * F_DIM + f] = sc;
        st[ST_SHIFT_FB + b * F_DIM + f] = bias[b * F_DIM + f] - mean * sc;
    }
}

#define APPLY_ROWS 4
__global__ __launch_bounds__(256) void cbn_apply_fb(const float* __restrict__ x,
                                                    const int* __restrict__ labels,
                                                    const float* __restrict__ st,
                                                    float* __restrict__ y) {
    const int nBlocks = NROWS / APPLY_ROWS;
    const int blk = nBlocks - 1 - blockIdx.x;
    const int row0 = blk * APPLY_ROWS;
#pragma unroll
    for (int it = 0; it < APPLY_ROWS; ++it) {
        const int row = row0 + it;
        const int b = row >> 7;
        const int f = row & (F_DIM - 1);
        const int k = labels[b];
        const float sc = st[ST_SCALE_FB + k * F_DIM + f];
        const float sh = st[ST_SHIFT_FB + k * F_DIM + f];
        const size_t i4 = (size_t)row * (L_DIM / 4) + threadIdx.x;
        vf4 v = reinterpret_cast<const vf4*>(x)[i4];
        vf4 o;
        o.x = v.x * sc + sh;
        o.y = v.y * sc + sh;
        o.z = v.z * sc + sh;
        o.w = v.w * sc + sh;
        __builtin_nontemporal_store(o, &reinterpret_cast<vf4*>(y)[i4]);
    }
}

extern "C" void kernel_launch(void* const* d_in, const int* in_sizes, int n_in,
                              void* d_out, int out_size, void* d_ws, size_t ws_size,
                              hipStream_t stream) {
    const float* x      = (const float*)d_in[0];
    const int*   labels = (const int*)d_in[1];
    const float* weight = (const float*)d_in[2];
    const float* bias   = (const float*)d_in[3];
    float* y  = (float*)d_out;
    float* ws = (float*)d_ws;
    uint*  gs = (uint*)((char*)d_ws + 2 * K_CLS * F_DIM * sizeof(float));

    int blocksPerCU = 0;
    hipError_t qerr = hipOccupancyMaxActiveBlocksPerMultiprocessor(
        &blocksPerCU, (const void*)cbn_fused, 256, 0);
    const bool coop_ok = (qerr == hipSuccess) && (blocksPerCU * 256 >= GRID);

    if (coop_ok) {
        hipMemsetAsync(ws, 0, 2 * K_CLS * F_DIM * sizeof(float) + 2 * sizeof(uint), stream);
        void* args[] = { (void*)&x, (void*)&labels, (void*)&weight, (void*)&bias,
                         (void*)&ws, (void*)&gs, (void*)&y };
        hipLaunchCooperativeKernel((const void*)cbn_fused, dim3(GRID), dim3(256),
                                   args, 0, stream);
    } else {
        cbn_stats_fb<<<NROWS / 4, 256, 0, stream>>>(x, ws);
        cbn_finalize_fb<<<F_DIM, 512, 0, stream>>>(labels, weight, bias, ws);
        cbn_apply_fb<<<NROWS / APPLY_ROWS, 256, 0, stream>>>(x, labels, ws, y);
    }
}